// Round 2
// baseline (1698.350 us; speedup 1.0000x reference)
//
#include <hip/hip_runtime.h>
#include <math.h>

#define FIN  1433
#define HID  16
#define NCLS 7
#define BM   128
#define BK   32

// K1: tiled dual GEMM  C[n x 32] = x[n x 1433] @ [w_rel1 | w_root1].
// Block: 256 threads -> 128 rows x 32 cols tile; thread computes 4x4.
// xs stored transposed [k][row] so compute reads are float4 over rows.
__global__ __launch_bounds__(256) void k1_gemm(
    const float* __restrict__ x,
    const float* __restrict__ w_root, const float* __restrict__ w_rel,
    const float* __restrict__ b_rel,
    float* __restrict__ p_rel, float* __restrict__ agg, int n) {
  __shared__ float xs[BK][BM + 4];   // +4 pad: breaks bank aliasing, keeps 16B align
  __shared__ float ws[BK][32];

  const int tid  = threadIdx.x;
  const int row0 = blockIdx.x * BM;
  const int cg   = tid & 7;          // col group: 4 cols each
  const int rg   = tid >> 3;         // row group: 4 rows each
  const int c0   = cg * 4;
  const int r0   = rg * 4;

  float acc[4][4];
#pragma unroll
  for (int i = 0; i < 4; ++i)
#pragma unroll
    for (int j = 0; j < 4; ++j) acc[i][j] = 0.f;

  const int KT = (FIN + BK - 1) / BK;   // 45
  for (int kt = 0; kt < KT; ++kt) {
    const int k0 = kt * BK;
    // stage x tile: 4096 elems, 16/thread, coalesced (consecutive tid -> consecutive k)
#pragma unroll
    for (int i = 0; i < 16; ++i) {
      int idx = i * 256 + tid;
      int r = idx >> 5, c = idx & 31;
      int gr = row0 + r, gk = k0 + c;
      float v = 0.f;
      if (gr < n && gk < FIN) v = x[(size_t)gr * FIN + gk];
      xs[c][r] = v;
    }
    // stage w tile: 1024 elems, 4/thread; cols 0-15 = w_rel, 16-31 = w_root
#pragma unroll
    for (int i = 0; i < 4; ++i) {
      int idx = i * 256 + tid;
      int kk = idx >> 5, c = idx & 31;
      int gk = k0 + kk;
      float v = 0.f;
      if (gk < FIN) v = (c < HID) ? w_rel[gk * HID + c] : w_root[gk * HID + (c - HID)];
      ws[kk][c] = v;
    }
    __syncthreads();
#pragma unroll
    for (int kk = 0; kk < BK; ++kk) {
      float4 xv = *(const float4*)&xs[kk][r0];
      float4 wv = *(const float4*)&ws[kk][c0];
      float xa[4] = {xv.x, xv.y, xv.z, xv.w};
      float wa[4] = {wv.x, wv.y, wv.z, wv.w};
#pragma unroll
      for (int i = 0; i < 4; ++i)
#pragma unroll
        for (int j = 0; j < 4; ++j)
          acc[i][j] = fmaf(xa[i], wa[j], acc[i][j]);
    }
    __syncthreads();
  }

  // epilogue: col groups 0-3 -> p_rel, 4-7 -> agg (+bias)
  if (cg < 4) {
#pragma unroll
    for (int i = 0; i < 4; ++i) {
      int gr = row0 + r0 + i;
      if (gr < n) {
        float4 v = {acc[i][0], acc[i][1], acc[i][2], acc[i][3]};
        *(float4*)&p_rel[(size_t)gr * HID + c0] = v;
      }
    }
  } else {
    const int cb = c0 - HID;
    float4 bv = *(const float4*)&b_rel[cb];
    float ba[4] = {bv.x, bv.y, bv.z, bv.w};
#pragma unroll
    for (int i = 0; i < 4; ++i) {
      int gr = row0 + r0 + i;
      if (gr < n) {
        float4 v = {acc[i][0] + ba[0], acc[i][1] + ba[1],
                    acc[i][2] + ba[2], acc[i][3] + ba[3]};
        *(float4*)&agg[(size_t)gr * HID + cb] = v;
      }
    }
  }
}

// K2: scatter-add 16-wide. 4 threads/edge, float4 gather + 4 atomics each.
__global__ __launch_bounds__(256) void k2_scatter16(
    const int* __restrict__ ei, const float* __restrict__ p,
    float* __restrict__ agg, int nE) {
  long long tid = (long long)blockIdx.x * 256 + threadIdx.x;
  int e = (int)(tid >> 2), q = (int)(tid & 3);
  if (e >= nE) return;
  int s = ei[e], d = ei[nE + e];
  float4 v = *(const float4*)(p + (size_t)s * HID + q * 4);
  float* dst = agg + (size_t)d * HID + q * 4;
  atomicAdd(dst + 0, v.x);
  atomicAdd(dst + 1, v.y);
  atomicAdd(dst + 2, v.z);
  atomicAdd(dst + 3, v.w);
}

// K3: ELU + dual 16x7 projection. out2 (=d_out) initialized with root part + bias.
__global__ __launch_bounds__(256) void k3_l2(
    const float* __restrict__ agg,
    const float* __restrict__ w_root2, const float* __restrict__ w_rel2,
    const float* __restrict__ b2,
    float* __restrict__ p2, float* __restrict__ out2, int n) {
  int i = blockIdx.x * 256 + threadIdx.x;
  if (i >= n) return;
  const float4* a4 = (const float4*)(agg + (size_t)i * HID);
  float h[HID];
#pragma unroll
  for (int q = 0; q < 4; ++q) {
    float4 v = a4[q];
    float t[4] = {v.x, v.y, v.z, v.w};
#pragma unroll
    for (int j = 0; j < 4; ++j)
      h[4*q + j] = t[j] > 0.f ? t[j] : expm1f(t[j]);
  }
#pragma unroll
  for (int c = 0; c < NCLS; ++c) {
    float sr = 0.f, so = b2[c];
#pragma unroll
    for (int k = 0; k < HID; ++k) {
      sr = fmaf(h[k], w_rel2[k * NCLS + c], sr);
      so = fmaf(h[k], w_root2[k * NCLS + c], so);
    }
    p2[(size_t)i * NCLS + c] = sr;
    out2[(size_t)i * NCLS + c] = so;
  }
}

// K4: scatter-add 7-wide. 8 threads/edge, lane 7 idle.
__global__ __launch_bounds__(256) void k4_scatter7(
    const int* __restrict__ ei, const float* __restrict__ p,
    float* __restrict__ out2, int nE) {
  long long tid = (long long)blockIdx.x * 256 + threadIdx.x;
  int e = (int)(tid >> 3), f = (int)(tid & 7);
  if (e >= nE || f >= NCLS) return;
  int s = ei[e], d = ei[nE + e];
  atomicAdd(out2 + (size_t)d * NCLS + f, p[(size_t)s * NCLS + f]);
}

// K5: in-place log_softmax over 7 classes.
__global__ __launch_bounds__(256) void k5_lsm(float* __restrict__ out, int n) {
  int i = blockIdx.x * 256 + threadIdx.x;
  if (i >= n) return;
  float v[NCLS];
  float* o = out + (size_t)i * NCLS;
#pragma unroll
  for (int c = 0; c < NCLS; ++c) v[c] = o[c];
  float m = v[0];
#pragma unroll
  for (int c = 1; c < NCLS; ++c) m = fmaxf(m, v[c]);
  float s = 0.f;
#pragma unroll
  for (int c = 0; c < NCLS; ++c) s += expf(v[c] - m);
  float l = logf(s);
#pragma unroll
  for (int c = 0; c < NCLS; ++c) o[c] = v[c] - m - l;
}

extern "C" void kernel_launch(void* const* d_in, const int* in_sizes, int n_in,
                              void* d_out, int out_size, void* d_ws, size_t ws_size,
                              hipStream_t stream) {
  const float* x       = (const float*)d_in[0];
  const int*   ei      = (const int*)  d_in[1];
  const float* w_root1 = (const float*)d_in[2];
  const float* w_rel1  = (const float*)d_in[3];
  const float* b_rel1  = (const float*)d_in[4];
  const float* w_root2 = (const float*)d_in[5];
  const float* w_rel2  = (const float*)d_in[6];
  const float* b_rel2  = (const float*)d_in[7];
  float* out = (float*)d_out;

  int n  = in_sizes[0] / FIN;   // 100000
  int nE = in_sizes[1] / 2;     // 3200000

  char* ws   = (char*)d_ws;
  float* p1   = (float*)ws;                                // n*16 f32
  float* agg1 = (float*)(ws + (size_t)n * HID * 4);        // n*16 f32
  float* p2   = (float*)(ws + (size_t)n * HID * 8);        // n*7  f32

  int nbRows = (n + BM - 1) / BM;   // 782
  k1_gemm<<<nbRows, 256, 0, stream>>>(x, w_root1, w_rel1, b_rel1, p1, agg1, n);

  long long t2 = (long long)nE * 4;
  k2_scatter16<<<(int)((t2 + 255) / 256), 256, 0, stream>>>(ei, p1, agg1, nE);

  int nb = (n + 255) / 256;
  k3_l2<<<nb, 256, 0, stream>>>(agg1, w_root2, w_rel2, b_rel2, p2, out, n);

  long long t4 = (long long)nE * 8;
  k4_scatter7<<<(int)((t4 + 255) / 256), 256, 0, stream>>>(ei, p2, out, nE);

  k5_lsm<<<nb, 256, 0, stream>>>(out, n);
}

// Round 3
// 599.057 us; speedup vs baseline: 2.8350x; 2.8350x over previous
//
#include <hip/hip_runtime.h>
#include <math.h>

#define FIN  1433
#define HID  16
#define NCLS 7
#define BM   128
#define BK   32
#define KS   2          // split-K slices
#define KT_TOTAL 45     // ceil(1433/32)
#define KT_HALF  23

// K1: split-K tiled dual GEMM  C[n x 32] = x[n x 1433] @ [w_rel1 | w_root1].
// grid = (ceil(n/128), 2). Slice 0 -> pa/aa (bias in aa), slice 1 -> pb/ab.
// LDS x-tile is XOR-swizzled: element (c,r) at xs[c*128 + (r^c)] ->
// conflict-free transposed writes AND float4 reads (static unpermute per kk).
// Register prefetch double-buffers the global loads across k-tiles.
__global__ __launch_bounds__(256) void k1_gemm(
    const float* __restrict__ x,
    const float* __restrict__ w_root, const float* __restrict__ w_rel,
    const float* __restrict__ b_rel,
    float* __restrict__ pa, float* __restrict__ pb,
    float* __restrict__ aa, float* __restrict__ ab, int n) {
  __shared__ float xs[BK * BM];   // 16 KB, swizzled
  __shared__ float ws[BK * 32];   // 4 KB

  const int tid   = threadIdx.x;
  const int row0  = blockIdx.x * BM;
  const int slice = blockIdx.y;
  const int cg    = tid & 7;
  const int rg    = tid >> 3;
  const int c0    = cg * 4;
  const int r0    = rg * 4;

  const int kt_beg = slice == 0 ? 0 : KT_HALF;
  const int kt_end = slice == 0 ? KT_HALF : KT_TOTAL;

  float acc[4][4];
#pragma unroll
  for (int i = 0; i < 4; ++i)
#pragma unroll
    for (int j = 0; j < 4; ++j) acc[i][j] = 0.f;

  float xreg[16], wreg[4];

  auto prefetch = [&](int kt) {
    const int k0 = kt * BK;
#pragma unroll
    for (int i = 0; i < 16; ++i) {
      int idx = i * 256 + tid;
      int r = idx >> 5, c = idx & 31;
      int gr = row0 + r, gk = k0 + c;
      xreg[i] = (gr < n && gk < FIN) ? x[(size_t)gr * FIN + gk] : 0.f;
    }
#pragma unroll
    for (int i = 0; i < 4; ++i) {
      int idx = i * 256 + tid;
      int kk = idx >> 5, c = idx & 31;
      int gk = k0 + kk;
      float v = 0.f;
      if (gk < FIN) v = (c < HID) ? w_rel[gk * HID + c] : w_root[gk * HID + (c - HID)];
      wreg[i] = v;
    }
  };

  prefetch(kt_beg);
  for (int kt = kt_beg; kt < kt_end; ++kt) {
    __syncthreads();   // previous tile's compute done -> LDS reusable
#pragma unroll
    for (int i = 0; i < 16; ++i) {
      int idx = i * 256 + tid;
      int r = idx >> 5, c = idx & 31;
      xs[c * BM + (r ^ c)] = xreg[i];
    }
#pragma unroll
    for (int i = 0; i < 4; ++i) {
      int idx = i * 256 + tid;
      int kk = idx >> 5, c = idx & 31;
      ws[kk * 32 + c] = wreg[i];
    }
    __syncthreads();
    if (kt + 1 < kt_end) prefetch(kt + 1);  // overlap next loads with compute
#pragma unroll
    for (int kk = 0; kk < BK; ++kk) {
      float4 xv = *(const float4*)&xs[kk * BM + ((r0 ^ kk) & ~3)];
      float4 wv = *(const float4*)&ws[kk * 32 + c0];
      float comp[4] = {xv.x, xv.y, xv.z, xv.w};
      const int p = kk & 3;  // compile-time (kk unrolled)
      float xa[4] = {comp[0 ^ p], comp[1 ^ p], comp[2 ^ p], comp[3 ^ p]};
      float wa[4] = {wv.x, wv.y, wv.z, wv.w};
#pragma unroll
      for (int i = 0; i < 4; ++i)
#pragma unroll
        for (int j = 0; j < 4; ++j)
          acc[i][j] = fmaf(xa[i], wa[j], acc[i][j]);
    }
  }

  float* __restrict__ p_out = slice == 0 ? pa : pb;
  float* __restrict__ a_out = slice == 0 ? aa : ab;
  if (cg < 4) {
#pragma unroll
    for (int i = 0; i < 4; ++i) {
      int gr = row0 + r0 + i;
      if (gr < n) {
        float4 v = {acc[i][0], acc[i][1], acc[i][2], acc[i][3]};
        *(float4*)&p_out[(size_t)gr * HID + c0] = v;
      }
    }
  } else {
    const int cb = c0 - HID;
    float b0 = 0.f, b1 = 0.f, b2v = 0.f, b3 = 0.f;
    if (slice == 0) { b0 = b_rel[cb]; b1 = b_rel[cb+1]; b2v = b_rel[cb+2]; b3 = b_rel[cb+3]; }
#pragma unroll
    for (int i = 0; i < 4; ++i) {
      int gr = row0 + r0 + i;
      if (gr < n) {
        float4 v = {acc[i][0] + b0, acc[i][1] + b1, acc[i][2] + b2v, acc[i][3] + b3};
        *(float4*)&a_out[(size_t)gr * HID + cb] = v;
      }
    }
  }
}

// KR: sum split-K partials in place: pa += pb, aa += ab (float4 granularity).
__global__ __launch_bounds__(256) void k_reduce(
    float* __restrict__ pa, const float* __restrict__ pb,
    float* __restrict__ aa, const float* __restrict__ ab, int n4) {
  int i = blockIdx.x * 256 + threadIdx.x;
  if (i >= n4) return;
  float4 a = ((const float4*)pa)[i], b = ((const float4*)pb)[i];
  a.x += b.x; a.y += b.y; a.z += b.z; a.w += b.w;
  ((float4*)pa)[i] = a;
  float4 c = ((const float4*)aa)[i], d = ((const float4*)ab)[i];
  c.x += d.x; c.y += d.y; c.z += d.z; c.w += d.w;
  ((float4*)aa)[i] = c;
}

// K2: scatter-add 16-wide. 16 threads per edge, 1 atomic each (R1 form).
__global__ __launch_bounds__(256) void k2_scatter16(
    const int* __restrict__ ei, const float* __restrict__ p,
    float* __restrict__ agg, int nE) {
  long long tid = (long long)blockIdx.x * 256 + threadIdx.x;
  if (tid >= (long long)nE * HID) return;
  int e = (int)(tid >> 4), f = (int)(tid & 15);
  int s = ei[e], d = ei[nE + e];
  atomicAdd(agg + (size_t)d * HID + f, p[(size_t)s * HID + f]);
}

// K3: ELU + dual 16x7 projection. out2 (=d_out) initialized with root part + bias.
__global__ __launch_bounds__(256) void k3_l2(
    const float* __restrict__ agg,
    const float* __restrict__ w_root2, const float* __restrict__ w_rel2,
    const float* __restrict__ b2,
    float* __restrict__ p2, float* __restrict__ out2, int n) {
  int i = blockIdx.x * 256 + threadIdx.x;
  if (i >= n) return;
  const float4* a4 = (const float4*)(agg + (size_t)i * HID);
  float h[HID];
#pragma unroll
  for (int q = 0; q < 4; ++q) {
    float4 v = a4[q];
    float t[4] = {v.x, v.y, v.z, v.w};
#pragma unroll
    for (int j = 0; j < 4; ++j)
      h[4*q + j] = t[j] > 0.f ? t[j] : expm1f(t[j]);
  }
#pragma unroll
  for (int c = 0; c < NCLS; ++c) {
    float sr = 0.f, so = b2[c];
#pragma unroll
    for (int k = 0; k < HID; ++k) {
      sr = fmaf(h[k], w_rel2[k * NCLS + c], sr);
      so = fmaf(h[k], w_root2[k * NCLS + c], so);
    }
    p2[(size_t)i * NCLS + c] = sr;
    out2[(size_t)i * NCLS + c] = so;
  }
}

// K4: scatter-add 7-wide. 8 threads/edge, lane 7 idle.
__global__ __launch_bounds__(256) void k4_scatter7(
    const int* __restrict__ ei, const float* __restrict__ p,
    float* __restrict__ out2, int nE) {
  long long tid = (long long)blockIdx.x * 256 + threadIdx.x;
  int e = (int)(tid >> 3), f = (int)(tid & 7);
  if (e >= nE || f >= NCLS) return;
  int s = ei[e], d = ei[nE + e];
  atomicAdd(out2 + (size_t)d * NCLS + f, p[(size_t)s * NCLS + f]);
}

// K5: in-place log_softmax over 7 classes.
__global__ __launch_bounds__(256) void k5_lsm(float* __restrict__ out, int n) {
  int i = blockIdx.x * 256 + threadIdx.x;
  if (i >= n) return;
  float v[NCLS];
  float* o = out + (size_t)i * NCLS;
#pragma unroll
  for (int c = 0; c < NCLS; ++c) v[c] = o[c];
  float m = v[0];
#pragma unroll
  for (int c = 1; c < NCLS; ++c) m = fmaxf(m, v[c]);
  float s = 0.f;
#pragma unroll
  for (int c = 0; c < NCLS; ++c) s += expf(v[c] - m);
  float l = logf(s);
#pragma unroll
  for (int c = 0; c < NCLS; ++c) o[c] = v[c] - m - l;
}

extern "C" void kernel_launch(void* const* d_in, const int* in_sizes, int n_in,
                              void* d_out, int out_size, void* d_ws, size_t ws_size,
                              hipStream_t stream) {
  const float* x       = (const float*)d_in[0];
  const int*   ei      = (const int*)  d_in[1];
  const float* w_root1 = (const float*)d_in[2];
  const float* w_rel1  = (const float*)d_in[3];
  const float* b_rel1  = (const float*)d_in[4];
  const float* w_root2 = (const float*)d_in[5];
  const float* w_rel2  = (const float*)d_in[6];
  const float* b_rel2  = (const float*)d_in[7];
  float* out = (float*)d_out;

  int n  = in_sizes[0] / FIN;   // 100000
  int nE = in_sizes[1] / 2;     // 3200000

  size_t seg = (size_t)n * HID * 4;   // 6.4 MB
  char* ws = (char*)d_ws;
  float* pa = (float*)(ws + 0 * seg);       // slice0 p_rel partial -> final p1
  float* pb = (float*)(ws + 1 * seg);       // slice1 p_rel partial
  float* aa = (float*)(ws + 2 * seg);       // slice0 agg partial   -> final agg
  float* ab = (float*)(ws + 3 * seg);       // slice1 agg partial
  float* p2 = (float*)(ws + 4 * seg);       // n*7 f32

  dim3 g1((n + BM - 1) / BM, KS);
  k1_gemm<<<g1, 256, 0, stream>>>(x, w_root1, w_rel1, b_rel1, pa, pb, aa, ab, n);

  int n4 = n * HID / 4;
  k_reduce<<<(n4 + 255) / 256, 256, 0, stream>>>(pa, pb, aa, ab, n4);

  long long t2 = (long long)nE * HID;
  k2_scatter16<<<(int)((t2 + 255) / 256), 256, 0, stream>>>(ei, pa, aa, nE);

  int nb = (n + 255) / 256;
  k3_l2<<<nb, 256, 0, stream>>>(aa, w_root2, w_rel2, b_rel2, p2, out, n);

  long long t4 = (long long)nE * 8;
  k4_scatter7<<<(int)((t4 + 255) / 256), 256, 0, stream>>>(ei, p2, out, nE);

  k5_lsm<<<nb, 256, 0, stream>>>(out, n);
}